// Round 11
// baseline (1090.214 us; speedup 1.0000x reference)
//
#include <hip/hip_runtime.h>

#define SEQ   2048
#define BATCH 4096
#define HID   6
#define BLK   256   // 4 waves/block; 8 elems/wave (2 streams x 4); 32 elems/block

typedef float v2f __attribute__((ext_vector_type(2)));
typedef unsigned u2 __attribute__((ext_vector_type(2)));

// ---- fast HW math ----
__device__ __forceinline__ float fexp2(float a) {
#if __has_builtin(__builtin_amdgcn_exp2f)
  return __builtin_amdgcn_exp2f(a);
#else
  float r; asm("v_exp_f32 %0, %1" : "=v"(r) : "v"(a)); return r;
#endif
}
__device__ __forceinline__ float frcp(float a) {
#if __has_builtin(__builtin_amdgcn_rcpf)
  return __builtin_amdgcn_rcpf(a);
#else
  float r; asm("v_rcp_f32 %0, %1" : "=v"(r) : "v"(a)); return r;
#endif
}

// ---- ds_swizzle broadcast of lane (8-group base + J) to the 8-group (R7-validated)
template <int OFF>
__device__ __forceinline__ float swzf(float v) {
  int r = __builtin_amdgcn_ds_swizzle(__builtin_bit_cast(int, v), OFF);
  return __builtin_bit_cast(float, r);
}
#define BC0 0x18
#define BC1 0x38
#define BC2 0x58
#define BC3 0x78
#define BC4 0x98
#define BC5 0xB8

// lane l <-> l^32 exchange via v_permlane32_swap_b32 (polarity validated R7 PASS)
__device__ __forceinline__ float xhalf(float v, bool hi) {
#if __has_builtin(__builtin_amdgcn_permlane32_swap)
  u2 r = __builtin_amdgcn_permlane32_swap(__builtin_bit_cast(unsigned, v),
                                          __builtin_bit_cast(unsigned, v), false, false);
  return __builtin_bit_cast(float, hi ? r.x : r.y);
#else
  unsigned d = __builtin_bit_cast(unsigned, v), s = d;
  asm volatile("v_permlane32_swap_b32 %0, %1" : "+v"(d), "+v"(s));
  return __builtin_bit_cast(float, hi ? d : s);
#endif
}

__global__ __launch_bounds__(BLK, 1) void lstm2_kernel(
    const float* __restrict__ x,
    const float* __restrict__ Wih0, const float* __restrict__ Whh0,
    const float* __restrict__ bih0, const float* __restrict__ bhh0,
    const float* __restrict__ Wih1, const float* __restrict__ Whh1,
    const float* __restrict__ bih1, const float* __restrict__ bhh1,
    const float* __restrict__ W2,   const float* __restrict__ b2,
    float* __restrict__ out)
{
  __shared__ float obuf[64][32];        // staged output rows (32 elems/block)
  __shared__ float xbuf[2][64][64];     // double-buffered 64-step x slices (16KB each)

  const int tid = threadIdx.x;
  const int wib = tid >> 6;            // wave in block 0..3
  const int l6  = tid & 63;
  const bool hi = l6 >= 32;            // false: layer-0 lanes, true: layer-1 lanes
  const int j   = l6 & 31;
  const int el  = j >> 3;              // element-slot within wave 0..3
  const int u   = j & 7;               // unit 0..7 (6,7 pads)
  const int uu  = (u < HID) ? u : (HID - 1);
  const int eA  = wib * 8 + el;        // stream-A element within block (0..31)
  const int eB  = eA + 4;              // stream-B element within block

  // Per-row constants (SHARED by both streams), rows q = 0..3 (i,f,g,o);
  // gate scale K folded into weights+bias; ABSOLUTE pair order (R7-validated).
  v2f WA[4][3], WB[4][3];
  float BS[4];
#pragma unroll
  for (int q = 0; q < 4; ++q) {
    const int rq = q * HID + uu;
    const float Kq = (q == 2) ? -2.8853900817779268f : -1.4426950408889634f;
    if (!hi) {
      WA[q][0] = v2f{Kq * Wih0[rq * 2 + 0], Kq * Wih0[rq * 2 + 1]};
      WA[q][1] = v2f{0.f, 0.f};
      WA[q][2] = v2f{0.f, 0.f};
#pragma unroll
      for (int k = 0; k < 3; ++k)
        WB[q][k] = v2f{Kq * Whh0[rq * HID + 2 * k], Kq * Whh0[rq * HID + 2 * k + 1]};
      BS[q] = Kq * (bih0[rq] + bhh0[rq]);
    } else {
#pragma unroll
      for (int k = 0; k < 3; ++k) {
        WA[q][k] = v2f{Kq * Wih1[rq * HID + 2 * k], Kq * Wih1[rq * HID + 2 * k + 1]};
        WB[q][k] = v2f{Kq * Whh1[rq * HID + 2 * k], Kq * Whh1[rq * HID + 2 * k + 1]};
      }
      BS[q] = Kq * (bih1[rq] + bhh1[rq]);
    }
  }
  const v2f w2p0 = v2f{W2[0], W2[1]}, w2p1 = v2f{W2[2], W2[3]}, w2p2 = v2f{W2[4], W2[5]};
  const float bout = b2[0];
  const float KT = 2.8853900817779268f;   // tanh(c) = 1 - 2*rcp(1+exp2(KT*c))

  // two independent streams: disjoint state, shared weights and lane roles
  float hA = 0.f, cA = 0.f, hB = 0.f, cB = 0.f;

  auto gath = [&](float hv, v2f (&g)[3]) {
    g[0] = v2f{swzf<BC0>(hv), swzf<BC1>(hv)};
    g[1] = v2f{swzf<BC2>(hv), swzf<BC3>(hv)};
    g[2] = v2f{swzf<BC4>(hv), swzf<BC5>(hv)};
  };

  // fused two-stream step: phases written A-then-B so every latency stall in
  // one stream has the other stream's independent instructions adjacent.
  auto step2 = [&](v2f xA, v2f xB, float& ovA, float& ovB) {
    v2f GA[3], GB[3];
    gath(hA, GA);                          // own-layer recurrence inputs
    gath(hB, GB);
    v2f HA[3], HB[3];                      // cross-layer (L1 input) via permlane
#pragma unroll
    for (int k = 0; k < 3; ++k) {
      HA[k] = v2f{xhalf(GA[k].x, hi), xhalf(GA[k].y, hi)};
      HB[k] = v2f{xhalf(GB[k].x, hi), xhalf(GB[k].y, hi)};
    }
    v2f vA = hi ? HA[0] : xA;
    v2f vB = hi ? HB[0] : xB;

    float aA[4], aB[4];
#pragma unroll
    for (int q = 0; q < 4; ++q) {
      v2f p = __builtin_elementwise_fma(WA[q][0], vA, v2f{BS[q], 0.f});
      p = __builtin_elementwise_fma(WA[q][1], HA[1], p);
      p = __builtin_elementwise_fma(WA[q][2], HA[2], p);
      v2f r = WB[q][0] * GA[0];
      r = __builtin_elementwise_fma(WB[q][1], GA[1], r);
      r = __builtin_elementwise_fma(WB[q][2], GA[2], r);
      v2f s = p + r;
      aA[q] = s.x + s.y;
    }
#pragma unroll
    for (int q = 0; q < 4; ++q) {
      v2f p = __builtin_elementwise_fma(WA[q][0], vB, v2f{BS[q], 0.f});
      p = __builtin_elementwise_fma(WA[q][1], HB[1], p);
      p = __builtin_elementwise_fma(WA[q][2], HB[2], p);
      v2f r = WB[q][0] * GB[0];
      r = __builtin_elementwise_fma(WB[q][1], GB[1], r);
      r = __builtin_elementwise_fma(WB[q][2], GB[2], r);
      v2f s = p + r;
      aB[q] = s.x + s.y;
    }

    v2f aoA = __builtin_elementwise_fma(w2p0, GA[0],
              __builtin_elementwise_fma(w2p1, GA[1],
              __builtin_elementwise_fma(w2p2, GA[2], v2f{bout, 0.f})));
    ovA = aoA.x + aoA.y;
    v2f aoB = __builtin_elementwise_fma(w2p0, GB[0],
              __builtin_elementwise_fma(w2p1, GB[1],
              __builtin_elementwise_fma(w2p2, GB[2], v2f{bout, 0.f})));
    ovB = aoB.x + aoB.y;

    // gates, math identical to R10 per stream
    float iA = frcp(1.f + fexp2(aA[0]));
    float fA = frcp(1.f + fexp2(aA[1]));
    float gA = fmaf(2.f, frcp(1.f + fexp2(aA[2])), -1.f);
    float oA = frcp(1.f + fexp2(aA[3]));
    float iB = frcp(1.f + fexp2(aB[0]));
    float fB = frcp(1.f + fexp2(aB[1]));
    float gB = fmaf(2.f, frcp(1.f + fexp2(aB[2])), -1.f);
    float oB = frcp(1.f + fexp2(aB[3]));
    cA = fmaf(fA, cA, iA * gA);
    cB = fmaf(fB, cB, iB * gB);
    float tA = fmaf(-2.f, frcp(1.f + fexp2(cA * KT)), 1.f);
    float tB = fmaf(-2.f, frcp(1.f + fexp2(cB * KT)), 1.f);
    hA = oA * tA;
    hB = oB * tB;
  };

  // bulk flush: 64 rows x 32 elements; 512 float4 / 256 threads = 2 each
  auto flush = [&](int rbase) {
#pragma unroll
    for (int k = 0; k < 2; ++k) {
      const int f = tid * 2 + k;
      const int row = f >> 3, off = (f & 7) * 4;
      float4 vv = *(const float4*)&obuf[row][off];
      *(float4*)&out[(size_t)(rbase + row) * BATCH + blockIdx.x * 32 + off] = vv;
    }
  };

  // ---- prologue: stage x chunks 0 and 1 into LDS ----
  {
    const int row = tid >> 2, cb = (tid & 3) * 16;
    const float* s0 = x + (size_t)row * (BATCH * 2) + blockIdx.x * 64 + cb;
    const float* s1 = s0 + (size_t)64 * (BATCH * 2);
    float4 a0 = *(const float4*)(s0 + 0),  a1 = *(const float4*)(s0 + 4);
    float4 a2 = *(const float4*)(s0 + 8),  a3 = *(const float4*)(s0 + 12);
    float4 b0 = *(const float4*)(s1 + 0),  b1 = *(const float4*)(s1 + 4);
    float4 b2v = *(const float4*)(s1 + 8), b3 = *(const float4*)(s1 + 12);
    *(float4*)&xbuf[0][row][cb + 0]  = a0;  *(float4*)&xbuf[0][row][cb + 4]  = a1;
    *(float4*)&xbuf[0][row][cb + 8]  = a2;  *(float4*)&xbuf[0][row][cb + 12] = a3;
    *(float4*)&xbuf[1][row][cb + 0]  = b0;  *(float4*)&xbuf[1][row][cb + 4]  = b1;
    *(float4*)&xbuf[1][row][cb + 8]  = b2v; *(float4*)&xbuf[1][row][cb + 12] = b3;
    __syncthreads();
  }

  v2f xrA = *(const v2f*)&xbuf[0][0][eA * 2];
  v2f xrB = *(const v2f*)&xbuf[0][0][eB * 2];

  // t = 0 peel: lo lanes compute h0[0]; hi lanes' result is garbage -> reset
  {
    float ovA, ovB;
    step2(xrA, xrB, ovA, ovB);
    if (hi) { hA = 0.f; cA = 0.f; hB = 0.f; cB = 0.f; }
    xrA = *(const v2f*)&xbuf[0][1][eA * 2];
    xrB = *(const v2f*)&xbuf[0][1][eB * 2];
  }

  // iteration t: lo -> h0[t]; hi -> h1[t-1]; out row t-2 from hi's gathers
#pragma unroll 1
  for (int t = 1; t < SEQ; ++t) {
    const int tn = (t + 1 < SEQ) ? t + 1 : SEQ - 1;
    v2f xnA = *(const v2f*)&xbuf[(tn >> 6) & 1][tn & 63][eA * 2];
    v2f xnB = *(const v2f*)&xbuf[(tn >> 6) & 1][tn & 63][eB * 2];

    float ovA, ovB;
    step2(xrA, xrB, ovA, ovB);

    if (t >= 2) {
      const int r = t - 2;
      if (hi && u == 0) { obuf[r & 63][eA] = ovA; obuf[r & 63][eB] = ovB; }
      if ((r & 63) == 63) {            // uniform branch, once per 64 steps
        const int ck = (t >> 6) + 1;   // next x chunk to stage
        const bool doR = (ck * 64 < SEQ);
        const int row = tid >> 2, cb = (tid & 3) * 16;
        float4 r0, r1, r2, r3;
        if (doR) {                     // issue loads BEFORE barrier
          const float* src = x + ((size_t)(ck * 64) + row) * (BATCH * 2)
                               + blockIdx.x * 64 + cb;
          r0 = *(const float4*)(src + 0);  r1 = *(const float4*)(src + 4);
          r2 = *(const float4*)(src + 8);  r3 = *(const float4*)(src + 12);
        }
        __syncthreads();
        flush(r - 63);
        if (doR) {
          *(float4*)&xbuf[ck & 1][row][cb + 0]  = r0;
          *(float4*)&xbuf[ck & 1][row][cb + 4]  = r1;
          *(float4*)&xbuf[ck & 1][row][cb + 8]  = r2;
          *(float4*)&xbuf[ck & 1][row][cb + 12] = r3;
        }
        __syncthreads();
      }
    }
    xrA = xnA; xrB = xnB;
  }

  // epilogue: one more fused step -> h1[S-1] + out row S-2; final gather -> row S-1
  {
    float ovA, ovB;
    step2(xrA, xrB, ovA, ovB);
    if (hi && u == 0) { obuf[62][eA] = ovA; obuf[62][eB] = ovB; }
    v2f GA[3], GB[3];
    gath(hA, GA);
    gath(hB, GB);
    v2f aoA = __builtin_elementwise_fma(w2p0, GA[0],
              __builtin_elementwise_fma(w2p1, GA[1],
              __builtin_elementwise_fma(w2p2, GA[2], v2f{bout, 0.f})));
    v2f aoB = __builtin_elementwise_fma(w2p0, GB[0],
              __builtin_elementwise_fma(w2p1, GB[1],
              __builtin_elementwise_fma(w2p2, GB[2], v2f{bout, 0.f})));
    if (hi && u == 0) { obuf[63][eA] = aoA.x + aoA.y; obuf[63][eB] = aoB.x + aoB.y; }
    __syncthreads();
    flush(SEQ - 64);
  }
}

extern "C" void kernel_launch(void* const* d_in, const int* in_sizes, int n_in,
                              void* d_out, int out_size, void* d_ws, size_t ws_size,
                              hipStream_t stream) {
  const float* x    = (const float*)d_in[0];
  const float* Wih0 = (const float*)d_in[1];
  const float* Whh0 = (const float*)d_in[2];
  const float* bih0 = (const float*)d_in[3];
  const float* bhh0 = (const float*)d_in[4];
  const float* Wih1 = (const float*)d_in[5];
  const float* Whh1 = (const float*)d_in[6];
  const float* bih1 = (const float*)d_in[7];
  const float* bhh1 = (const float*)d_in[8];
  const float* W2   = (const float*)d_in[9];
  const float* b2   = (const float*)d_in[10];
  float* out = (float*)d_out;

  dim3 grid(BATCH / 32);   // 128 blocks x 4 waves; 8 elems/wave (2 streams)
  dim3 block(BLK);
  hipLaunchKernelGGL(lstm2_kernel, grid, block, 0, stream,
                     x, Wih0, Whh0, bih0, bhh0, Wih1, Whh1, bih1, bhh1, W2, b2, out);
}

// Round 12
// 819.583 us; speedup vs baseline: 1.3302x; 1.3302x over previous
//
#include <hip/hip_runtime.h>

#define SEQ   2048
#define BATCH 4096
#define HID   6
#define BLK   128   // 2 waves/block: wave0 = layer-0, wave1 = layer-1; 8 elems/block

typedef float v2f __attribute__((ext_vector_type(2)));

// ---- fast HW math ----
__device__ __forceinline__ float fexp2(float a) {
#if __has_builtin(__builtin_amdgcn_exp2f)
  return __builtin_amdgcn_exp2f(a);
#else
  float r; asm("v_exp_f32 %0, %1" : "=v"(r) : "v"(a)); return r;
#endif
}
__device__ __forceinline__ float frcp(float a) {
#if __has_builtin(__builtin_amdgcn_rcpf)
  return __builtin_amdgcn_rcpf(a);
#else
  float r; asm("v_rcp_f32 %0, %1" : "=v"(r) : "v"(a)); return r;
#endif
}

// ---- DPP cross-lane (VALU pipe; R8-validated gather scheme) ----
template <int CTRL>
__device__ __forceinline__ float dppf(float v) {
  int r = __builtin_amdgcn_update_dpp(0, __builtin_bit_cast(int, v), CTRL, 0xF, 0xF, true);
  return __builtin_bit_cast(float, r);
}
// 0xB1 quad_perm[1,0,3,2]=xor1; 0x4E quad_perm[2,3,0,1]=xor2; 0x141 row_half_mirror=xor7 on 8-group

__global__ __launch_bounds__(BLK, 1) void lstm2_kernel(
    const float* __restrict__ x,
    const float* __restrict__ Wih0, const float* __restrict__ Whh0,
    const float* __restrict__ bih0, const float* __restrict__ bhh0,
    const float* __restrict__ Wih1, const float* __restrict__ Whh1,
    const float* __restrict__ bih1, const float* __restrict__ bhh1,
    const float* __restrict__ W2,   const float* __restrict__ b2,
    float* __restrict__ out)
{
  __shared__ float xbuf[2][64][16];   // 64-step x slices, double-buffered (4KB each)
  __shared__ float obuf[64][8];       // staged output rows
  __shared__ float ring[2][8][8];     // h0 handoff ring, depth 2 (write t&1, read (t-1)&1)

  const int tid = threadIdx.x;
  const int wib = tid >> 6;           // 0 = layer-0 wave, 1 = layer-1 wave
  const int l6  = tid & 63;
  const int el  = l6 >> 3;            // element within block 0..7
  const int u   = l6 & 7;             // unit 0..7 (6,7 pads)
  const int uu  = (u < HID) ? u : (HID - 1);

  // Per-gate-row constants, q = 0..3 (i,f,g,o); scale Kq folded into weights+bias.
  // WIN = input-side dot (L0: x pair in slot 0; L1: absolute h0 pairs, R7-validated).
  // WRr = own-layer recurrence in XOR-RELATIVE pair order (R8-validated vs 7-DPP gather).
  v2f WIN[4][3], WRr[4][4], w2r[4];
  float BS[4];
#pragma unroll
  for (int q = 0; q < 4; ++q) {
    const int rq = q * HID + uu;
    const float Kq = (q == 2) ? -2.8853900817779268f : -1.4426950408889634f;
    if (wib == 0) {
      WIN[q][0] = v2f{Kq * Wih0[rq * 2 + 0], Kq * Wih0[rq * 2 + 1]};
      WIN[q][1] = v2f{0.f, 0.f};
      WIN[q][2] = v2f{0.f, 0.f};
#pragma unroll
      for (int k = 0; k < 4; ++k) {
        const int k0 = u ^ (2 * k), k1 = u ^ (2 * k + 1);
        WRr[q][k] = v2f{(k0 < HID) ? Kq * Whh0[rq * HID + k0] : 0.f,
                        (k1 < HID) ? Kq * Whh0[rq * HID + k1] : 0.f};
      }
      BS[q] = Kq * (bih0[rq] + bhh0[rq]);
    } else {
#pragma unroll
      for (int k = 0; k < 3; ++k)
        WIN[q][k] = v2f{Kq * Wih1[rq * HID + 2 * k], Kq * Wih1[rq * HID + 2 * k + 1]};
#pragma unroll
      for (int k = 0; k < 4; ++k) {
        const int k0 = u ^ (2 * k), k1 = u ^ (2 * k + 1);
        WRr[q][k] = v2f{(k0 < HID) ? Kq * Whh1[rq * HID + k0] : 0.f,
                        (k1 < HID) ? Kq * Whh1[rq * HID + k1] : 0.f};
      }
      BS[q] = Kq * (bih1[rq] + bhh1[rq]);
    }
  }
#pragma unroll
  for (int k = 0; k < 4; ++k) {
    const int k0 = u ^ (2 * k), k1 = u ^ (2 * k + 1);
    w2r[k] = v2f{(k0 < HID) ? W2[k0] : 0.f, (k1 < HID) ? W2[k1] : 0.f};
  }
  const float bout = b2[0];
  const float KT = 2.8853900817779268f;   // tanh(c) = 1 - 2*rcp(1+exp2(KT*c))

  float h = 0.f, c = 0.f;   // own-layer state (wave0: h0/c0, wave1: h1/c1)

  // 7-DPP xor-relative all-gather over the 8-group (R8-validated pairing)
  auto gath = [&](float hv, v2f (&g)[4]) {
    float t1 = dppf<0xB1>(hv);       // xor1
    float t2 = dppf<0x4E>(hv);       // xor2
    float t3 = dppf<0x4E>(t1);       // xor3
    float m  = dppf<0x141>(hv);      // xor7
    float m1 = dppf<0xB1>(m);        // xor6
    float m2 = dppf<0x4E>(m);        // xor5
    float m3 = dppf<0x4E>(m1);       // xor4
    g[0] = v2f{hv, t1};
    g[1] = v2f{t2, t3};
    g[2] = v2f{m3, m2};
    g[3] = v2f{m1, m};
  };

  // unified cell step: a = BS + WIN·(in0,in1,in2) + WRr·gather(h); gates -> c,h
  auto cell = [&](v2f in0, v2f in1, v2f in2, v2f (&g)[4]) {
    gath(h, g);
    float a[4];
#pragma unroll
    for (int q = 0; q < 4; ++q) {
      v2f acc = __builtin_elementwise_fma(WIN[q][0], in0, v2f{BS[q], 0.f});
      acc = __builtin_elementwise_fma(WIN[q][1], in1, acc);
      acc = __builtin_elementwise_fma(WIN[q][2], in2, acc);
      acc = __builtin_elementwise_fma(WRr[q][0], g[0], acc);
      acc = __builtin_elementwise_fma(WRr[q][1], g[1], acc);
      acc = __builtin_elementwise_fma(WRr[q][2], g[2], acc);
      acc = __builtin_elementwise_fma(WRr[q][3], g[3], acc);
      a[q] = acc.x + acc.y;
    }
    float i_ = frcp(1.f + fexp2(a[0]));
    float f_ = frcp(1.f + fexp2(a[1]));
    float g_ = fmaf(2.f, frcp(1.f + fexp2(a[2])), -1.f);
    float o_ = frcp(1.f + fexp2(a[3]));
    c = fmaf(f_, c, i_ * g_);
    float th = fmaf(-2.f, frcp(1.f + fexp2(c * KT)), 1.f);
    h = o_ * th;
  };

  auto outdot = [&](const v2f (&g)[4]) -> float {
    v2f ao = __builtin_elementwise_fma(w2r[0], g[0],
             __builtin_elementwise_fma(w2r[1], g[1],
             __builtin_elementwise_fma(w2r[2], g[2],
             __builtin_elementwise_fma(w2r[3], g[3], v2f{bout, 0.f}))));
    return ao.x + ao.y;
  };

  // flush: 64 rows x 8 elems; 128 threads x 1 float4
  auto flush = [&](int rbase) {
    const int r = tid >> 1, off = (tid & 1) * 4;
    float4 vv = *(const float4*)&obuf[r][off];
    *(float4*)&out[(size_t)(rbase + r) * BATCH + blockIdx.x * 8 + off] = vv;
  };

  // ---- prologue: stage x chunks 0,1 (each thread: row=tid>>1, 8 floats) ----
  {
    const int row = tid >> 1, off = (tid & 1) * 8;
    const float* s0 = x + (size_t)row * (BATCH * 2) + blockIdx.x * 16 + off;
    const float* s1 = s0 + (size_t)64 * (BATCH * 2);
    float4 a0 = *(const float4*)s0, a1 = *(const float4*)(s0 + 4);
    float4 b0 = *(const float4*)s1, b1 = *(const float4*)(s1 + 4);
    *(float4*)&xbuf[0][row][off]     = a0;
    *(float4*)&xbuf[0][row][off + 4] = a1;
    *(float4*)&xbuf[1][row][off]     = b0;
    *(float4*)&xbuf[1][row][off + 4] = b1;
    __syncthreads();
  }

  const v2f Z = v2f{0.f, 0.f};
  v2f xr = *(const v2f*)&xbuf[0][0][el * 2];

  // t = 0 peel: wave0 computes h0[0] (all h-inputs zero); wave1 result discarded
  {
    v2f g[4];
    cell(wib ? Z : xr, Z, Z, g);
    if (wib) { h = 0.f; c = 0.f; }
    else if (u < HID) ring[0][el][u] = h;
    xr = *(const v2f*)&xbuf[0][1][el * 2];
    __syncthreads();
  }

  // iteration t: wave0 -> h0[t] (x[t], h0[t-1]); wave1 -> h1[t-1] (ring h0[t-1], h1[t-2]);
  // out row t-2 from wave1's own-gather (= h1[t-2]).
#pragma unroll 1
  for (int t = 1; t < SEQ; ++t) {
    v2f hp0 = Z, hp1 = Z, hp2 = Z, xnew = xr;
    if (wib) {                         // wave-uniform: L1 reads h0[t-1] from ring
      const v2f* hp = (const v2f*)&ring[(t - 1) & 1][el][0];
      hp0 = hp[0]; hp1 = hp[1]; hp2 = hp[2];
    } else {                           // wave-uniform: L0 prefetches x 1 step ahead
      const int tn = (t + 1 < SEQ) ? t + 1 : SEQ - 1;
      xnew = *(const v2f*)&xbuf[(tn >> 6) & 1][tn & 63][el * 2];
    }

    v2f g[4];
    cell(wib ? hp0 : xr, hp1, hp2, g);

    if (wib) {
      if (t >= 2 && u == 0) obuf[(t - 2) & 63][el] = outdot(g);
    } else {
      if (u < HID) ring[t & 1][el][u] = h;
    }

    if (t >= 2 && ((t - 2) & 63) == 63) {   // uniform: flush + x restage per 64 steps
      const int ck = (t >> 6) + 1;
      const bool doR = (ck * 64 < SEQ);
      const int row = tid >> 1, off = (tid & 1) * 8;
      float4 r0, r1;
      if (doR) {
        const float* src = x + ((size_t)(ck * 64) + row) * (BATCH * 2)
                             + blockIdx.x * 16 + off;
        r0 = *(const float4*)src;
        r1 = *(const float4*)(src + 4);
      }
      __syncthreads();
      flush(t - 2 - 63);
      if (doR) {
        *(float4*)&xbuf[ck & 1][row][off]     = r0;
        *(float4*)&xbuf[ck & 1][row][off + 4] = r1;
      }
    }
    __syncthreads();                   // per-step producer/consumer barrier
    xr = xnew;
  }

  // epilogue (wave1): one more L1 step -> h1[S-1] + out rows S-2, S-1
  if (wib) {
    const v2f* hp = (const v2f*)&ring[(SEQ - 1) & 1][el][0];
    v2f hp0 = hp[0], hp1 = hp[1], hp2 = hp[2];
    v2f g[4];
    cell(hp0, hp1, hp2, g);            // gathers h1[S-2] first -> row S-2
    if (u == 0) obuf[62][el] = outdot(g);
    v2f g2[4]; gath(h, g2);            // h1[S-1] -> row S-1
    if (u == 0) obuf[63][el] = outdot(g2);
  }
  __syncthreads();
  flush(SEQ - 64);
}

extern "C" void kernel_launch(void* const* d_in, const int* in_sizes, int n_in,
                              void* d_out, int out_size, void* d_ws, size_t ws_size,
                              hipStream_t stream) {
  const float* x    = (const float*)d_in[0];
  const float* Wih0 = (const float*)d_in[1];
  const float* Whh0 = (const float*)d_in[2];
  const float* bih0 = (const float*)d_in[3];
  const float* bhh0 = (const float*)d_in[4];
  const float* Wih1 = (const float*)d_in[5];
  const float* Whh1 = (const float*)d_in[6];
  const float* bih1 = (const float*)d_in[7];
  const float* bhh1 = (const float*)d_in[8];
  const float* W2   = (const float*)d_in[9];
  const float* b2   = (const float*)d_in[10];
  float* out = (float*)d_out;

  dim3 grid(BATCH / 8);   // 512 blocks x 2 waves = 1024 waves = 1 wave/SIMD
  dim3 block(BLK);
  hipLaunchKernelGGL(lstm2_kernel, grid, block, 0, stream,
                     x, Wih0, Whh0, bih0, bhh0, Wih1, Whh1, bih1, bhh1, W2, b2, out);
}